// Round 5
// baseline (313.792 us; speedup 1.0000x reference)
//
#include <hip/hip_runtime.h>

#define B 4
#define S 2048
#define H 16
#define D 64
#define E 1024
#define BH (B*H)

typedef __bf16 bf16;
typedef __bf16 bf16x8 __attribute__((ext_vector_type(8)));
typedef __bf16 bf16x4 __attribute__((ext_vector_type(4)));
typedef float  f32x4  __attribute__((ext_vector_type(4)));

__device__ __forceinline__ f32x4 mfma16(bf16x8 a, bf16x8 b, f32x4 c) {
    return __builtin_amdgcn_mfma_f32_16x16x32_bf16(a, b, c, 0, 0, 0);
}

#define SCALE 0.04508422002778f   // (1/sqrt(1024)) * log2(e), folded into Q

// ---------------------------------------------------------------------------
// Kernel 1: QKV projection, LDS-free. Block = (s-tile of 128, bh, type);
// 4 waves x 32 rows.
// type 0: query@Wq^T (pre-scaled) -> qp [bh][s][d]   (swapped operands, b64)
// type 1: keys@Wk^T -> kp [bh][s][d]                 (swapped operands, b64)
// type 2: values@Wv^T -> vtt TILED [bh][s/64][d][s%64] (8 KB contiguous tiles)
// ---------------------------------------------------------------------------
__global__ __launch_bounds__(256) void proj_kernel(
    const float* __restrict__ values, const float* __restrict__ keys,
    const float* __restrict__ query,  const float* __restrict__ Wv,
    const float* __restrict__ Wk,     const float* __restrict__ Wq,
    bf16* __restrict__ qp, bf16* __restrict__ kp, bf16* __restrict__ vtt)
{
    const int t    = threadIdx.x;
    const int bh   = blockIdx.y;
    const int type = blockIdx.z;
    const int b = bh >> 4, h = bh & 15;
    const int s0 = blockIdx.x * 128;
    const int w = t >> 6, lane = t & 63;
    const int m = lane & 15, g = lane >> 4;
    const int row0 = s0 + w * 32;

    const float* X = (type == 0) ? query : (type == 1) ? keys : values;
    const float* W = (type == 0) ? Wq    : (type == 1) ? Wk   : Wv;

    bf16x8 xa[2][2];
    #pragma unroll
    for (int mt = 0; mt < 2; ++mt)
        #pragma unroll
        for (int kb = 0; kb < 2; ++kb) {
            const float* px = X + (size_t)(b * S + row0 + mt * 16 + m) * E + h * D + kb * 32 + g * 8;
            f32x4 lo = *(const f32x4*)px;
            f32x4 hi = *(const f32x4*)(px + 4);
            if (type == 0) { lo *= SCALE; hi *= SCALE; }
            bf16x8 f;
            #pragma unroll
            for (int i = 0; i < 4; ++i) { f[i] = (bf16)lo[i]; f[4 + i] = (bf16)hi[i]; }
            xa[mt][kb] = f;
        }

    bf16x8 wf[4][2];
    #pragma unroll
    for (int nt = 0; nt < 4; ++nt)
        #pragma unroll
        for (int kb = 0; kb < 2; ++kb) {
            const float* pw = W + (nt * 16 + m) * 64 + kb * 32 + g * 8;
            f32x4 lo = *(const f32x4*)pw;
            f32x4 hi = *(const f32x4*)(pw + 4);
            bf16x8 f;
            #pragma unroll
            for (int i = 0; i < 4; ++i) { f[i] = (bf16)lo[i]; f[4 + i] = (bf16)hi[i]; }
            wf[nt][kb] = f;
        }

    if (type == 2) {
        // D[s][d]: lane col = d = nt*16+m, rows s = mt*16+g*4+i -> b64 along s
        // tiled store: vtt[((bh*32 + st)*64 + d)*64 + si]
        #pragma unroll
        for (int mt = 0; mt < 2; ++mt) {
            int soff = w * 32 + mt * 16;
            int st = (s0 + soff) >> 6;
            int si = (soff & 63) + g * 4;
            #pragma unroll
            for (int nt = 0; nt < 4; ++nt) {
                f32x4 acc = (f32x4){0.f, 0.f, 0.f, 0.f};
                acc = mfma16(xa[mt][0], wf[nt][0], acc);
                acc = mfma16(xa[mt][1], wf[nt][1], acc);
                bf16x4 pk = __builtin_convertvector(acc, bf16x4);
                *(bf16x4*)(vtt + ((size_t)(bh * 32 + st) * 64 + nt * 16 + m) * 64 + si) = pk;
            }
        }
    } else {
        // swapped: D[d][s]: lane col = s, rows d -> b64 stores along d
        bf16* out = (type == 0) ? qp : kp;
        #pragma unroll
        for (int mt = 0; mt < 2; ++mt)
            #pragma unroll
            for (int nt = 0; nt < 4; ++nt) {
                f32x4 acc = (f32x4){0.f, 0.f, 0.f, 0.f};
                acc = mfma16(wf[nt][0], xa[mt][0], acc);
                acc = mfma16(wf[nt][1], xa[mt][1], acc);
                bf16x4 pk = __builtin_convertvector(acc, bf16x4);
                *(bf16x4*)(out + (size_t)(bh * S + row0 + mt * 16 + m) * D + nt * 16 + g * 4) = pk;
            }
    }
}

// ---------------------------------------------------------------------------
// Kernel 2: BARRIER-FREE flash attention, static softmax.
// K/V fragments loaded directly from global (K tiles and tiled-V tiles are
// 8 KB contiguous -> L1 serves the 4x per-block re-read). No __syncthreads.
// LDS holds only the per-wave P round-trip. PV computed as O^T = V^T P^T so
// the epilogue is b64 stores and 1/L is a per-lane scalar (ones as A-operand).
// ---------------------------------------------------------------------------
#define PSTR 72

__global__ __launch_bounds__(256, 2) void attn_kernel(
    const bf16* __restrict__ qp, const bf16* __restrict__ kp,
    const bf16* __restrict__ vtt, bf16* __restrict__ attn)
{
    const int t  = threadIdx.x;
    const int bh = blockIdx.y;
    const int b  = bh >> 4, h = bh & 15;
    const int q0 = blockIdx.x * 256;
    const int w  = t >> 6, lane = t & 63;
    const int m  = lane & 15, g = lane >> 4;

    __shared__ bf16 Ps[4][64 * PSTR];   // per-wave P [q_local 64][key_local 64]

    bf16x8 qa[4][2];
    #pragma unroll
    for (int mt = 0; mt < 4; ++mt)
        #pragma unroll
        for (int kb = 0; kb < 2; ++kb)
            qa[mt][kb] = *(const bf16x8*)(qp + (size_t)(bh * S + q0 + w * 64 + mt * 16 + m) * D + kb * 32 + g * 8);

    bf16x8 ones;
    #pragma unroll
    for (int i = 0; i < 8; ++i) ones[i] = (bf16)1.0f;

    f32x4 O[4][4], L[4];    // O[mt][dt] holds O^T tile: rows d, cols q
    #pragma unroll
    for (int mt = 0; mt < 4; ++mt) {
        L[mt] = (f32x4){0.f, 0.f, 0.f, 0.f};
        #pragma unroll
        for (int dt = 0; dt < 4; ++dt) O[mt][dt] = (f32x4){0.f, 0.f, 0.f, 0.f};
    }

    const bf16* kbase = kp  + (size_t)bh * S * D;
    const bf16* vbase = vtt + (size_t)bh * S * D;   // tiled: [kt][d][64]

    // kf fragments for tile 0 (prefetched; next tile's loaded during PV)
    bf16x8 kf[4][2];
    #pragma unroll
    for (int nt = 0; nt < 4; ++nt)
        #pragma unroll
        for (int kb = 0; kb < 2; ++kb)
            kf[nt][kb] = *(const bf16x8*)(kbase + (size_t)(nt * 16 + m) * D + kb * 32 + g * 8);

    for (int kt = 0; kt < S / 64; ++kt) {
        // V fragments for this tile — in flight during QK/exp2
        bf16x8 vf[4][2];
        #pragma unroll
        for (int dt = 0; dt < 4; ++dt)
            #pragma unroll
            for (int kb = 0; kb < 2; ++kb)
                vf[dt][kb] = *(const bf16x8*)(vbase + (size_t)kt * 4096 + (dt * 16 + m) * 64 + kb * 32 + g * 8);

        // ---- E^T = K Q^T; exp2; b64 P stores (4 consecutive keys/lane) ----
        #pragma unroll
        for (int nt = 0; nt < 4; ++nt)
            #pragma unroll
            for (int mt = 0; mt < 4; ++mt) {
                f32x4 et = (f32x4){0.f, 0.f, 0.f, 0.f};
                et = mfma16(kf[nt][0], qa[mt][0], et);
                et = mfma16(kf[nt][1], qa[mt][1], et);
                bf16x4 pkt;
                #pragma unroll
                for (int i = 0; i < 4; ++i)
                    pkt[i] = (bf16)__builtin_amdgcn_exp2f(et[i]);
                *(bf16x4*)(&Ps[w][(mt * 16 + m) * PSTR + nt * 16 + g * 4]) = pkt;
            }
        // per-wave private LDS region; same-wave ds ordering via lgkmcnt

        bf16x8 pa[4][2];
        #pragma unroll
        for (int mt = 0; mt < 4; ++mt)
            #pragma unroll
            for (int kb = 0; kb < 2; ++kb)
                pa[mt][kb] = *(const bf16x8*)(&Ps[w][(mt * 16 + m) * PSTR + kb * 32 + g * 8]);

        // prefetch next tile's K fragments — in flight during PV
        if (kt + 1 < S / 64) {
            #pragma unroll
            for (int nt = 0; nt < 4; ++nt)
                #pragma unroll
                for (int kb = 0; kb < 2; ++kb)
                    kf[nt][kb] = *(const bf16x8*)(kbase + (size_t)((kt + 1) * 64 + nt * 16 + m) * D + kb * 32 + g * 8);
        }

        // ---- O^T += V^T P^T ; L += ones·P^T (per-lane q column sums) ----
        #pragma unroll
        for (int dt = 0; dt < 4; ++dt)
            #pragma unroll
            for (int mt = 0; mt < 4; ++mt) {
                O[mt][dt] = mfma16(vf[dt][0], pa[mt][0], O[mt][dt]);
                O[mt][dt] = mfma16(vf[dt][1], pa[mt][1], O[mt][dt]);
            }
        #pragma unroll
        for (int mt = 0; mt < 4; ++mt) {
            L[mt] = mfma16(ones, pa[mt][0], L[mt]);
            L[mt] = mfma16(ones, pa[mt][1], L[mt]);
        }
    }

    // ---- epilogue: lane holds col q = mt*16+m; rows d = dt*16+g*4+i ----
    #pragma unroll
    for (int mt = 0; mt < 4; ++mt) {
        float linv = 1.f / L[mt][0];   // all 4 regs identical (ones as A)
        #pragma unroll
        for (int dt = 0; dt < 4; ++dt) {
            bf16x4 o;
            #pragma unroll
            for (int i = 0; i < 4; ++i) o[i] = (bf16)(O[mt][dt][i] * linv);
            *(bf16x4*)(attn + (size_t)(b * S + q0 + w * 64 + mt * 16 + m) * E + h * D + dt * 16 + g * 4) = o;
        }
    }
}

// ---------------------------------------------------------------------------
// Kernel 2.5: Wo fp32 -> bf16
// ---------------------------------------------------------------------------
__global__ __launch_bounds__(256) void wo_convert(
    const float* __restrict__ Wo, bf16* __restrict__ wb)
{
    int i = (blockIdx.x * 256 + threadIdx.x) * 4;
    f32x4 v = *(const f32x4*)(Wo + i);
    *(bf16x4*)(wb + i) = __builtin_convertvector(v, bf16x4);
}

// ---------------------------------------------------------------------------
// Kernel 3: out = attn @ Wo^T + bo. 128x128 tile, BK=64, swapped operands
// (Wo as A) so stores are f32x4; register prefetch of next K-slab.
// ---------------------------------------------------------------------------
__global__ __launch_bounds__(256) void out_gemm(
    const bf16* __restrict__ A, const bf16* __restrict__ wo,
    const float* __restrict__ bo, float* __restrict__ out)
{
    const int t  = threadIdx.x;
    const int n0 = blockIdx.x * 128;
    const int m0 = blockIdx.y * 128;
    const int w  = t >> 6, lane = t & 63;
    const int m  = lane & 15, g = lane >> 4;
    const int wm = w >> 1, wn = w & 1;

    __shared__ bf16 As[128 * 72];
    __shared__ bf16 Bs[128 * 72];

    f32x4 acc[4][4];
    #pragma unroll
    for (int mt = 0; mt < 4; ++mt)
        #pragma unroll
        for (int nt = 0; nt < 4; ++nt) acc[mt][nt] = (f32x4){0.f, 0.f, 0.f, 0.f};

    bf16x8 pA[4], pB[4];
    #pragma unroll
    for (int p = 0; p < 4; ++p) {
        int id = p * 256 + t;
        int row = id >> 3, ch = (id & 7) * 8;
        pA[p] = *(const bf16x8*)(A  + (size_t)(m0 + row) * E + ch);
        pB[p] = *(const bf16x8*)(wo + (size_t)(n0 + row) * E + ch);
    }

    for (int kt = 0; kt < E / 64; ++kt) {
        __syncthreads();
        #pragma unroll
        for (int p = 0; p < 4; ++p) {
            int id = p * 256 + t;
            int row = id >> 3, ch = (id & 7) * 8;
            *(bf16x8*)(As + row * 72 + ch) = pA[p];
            *(bf16x8*)(Bs + row * 72 + ch) = pB[p];
        }
        __syncthreads();
        if (kt + 1 < E / 64) {
            #pragma unroll
            for (int p = 0; p < 4; ++p) {
                int id = p * 256 + t;
                int row = id >> 3, ch = (id & 7) * 8;
                pA[p] = *(const bf16x8*)(A  + (size_t)(m0 + row) * E + (kt + 1) * 64 + ch);
                pB[p] = *(const bf16x8*)(wo + (size_t)(n0 + row) * E + (kt + 1) * 64 + ch);
            }
        }

        #pragma unroll
        for (int kb = 0; kb < 2; ++kb) {
            bf16x8 af[4], bfr[4];
            #pragma unroll
            for (int mt = 0; mt < 4; ++mt)
                af[mt] = *(const bf16x8*)(As + (wm * 64 + mt * 16 + m) * 72 + kb * 32 + g * 8);
            #pragma unroll
            for (int nt = 0; nt < 4; ++nt)
                bfr[nt] = *(const bf16x8*)(Bs + (wn * 64 + nt * 16 + m) * 72 + kb * 32 + g * 8);
            #pragma unroll
            for (int mt = 0; mt < 4; ++mt)
                #pragma unroll
                for (int nt = 0; nt < 4; ++nt)
                    acc[mt][nt] = mfma16(bfr[nt], af[mt], acc[mt][nt]);
        }
    }

    #pragma unroll
    for (int mt = 0; mt < 4; ++mt)
        #pragma unroll
        for (int nt = 0; nt < 4; ++nt) {
            f32x4 bias = *(const f32x4*)(bo + n0 + wn * 64 + nt * 16 + g * 4);
            f32x4 res = acc[mt][nt] + bias;
            *(f32x4*)(out + (size_t)(m0 + wm * 64 + mt * 16 + m) * E + n0 + wn * 64 + nt * 16 + g * 4) = res;
        }
}

// ---------------------------------------------------------------------------
extern "C" void kernel_launch(void* const* d_in, const int* in_sizes, int n_in,
                              void* d_out, int out_size, void* d_ws, size_t ws_size,
                              hipStream_t stream) {
    const float* values = (const float*)d_in[0];
    const float* keys   = (const float*)d_in[1];
    const float* query  = (const float*)d_in[2];
    const float* Wv     = (const float*)d_in[3];
    const float* Wk     = (const float*)d_in[4];
    const float* Wq     = (const float*)d_in[5];
    const float* Wo     = (const float*)d_in[6];
    const float* bo     = (const float*)d_in[7];
    float* out = (float*)d_out;

    bf16* qp   = (bf16*)d_ws;
    bf16* kp   = qp + (size_t)BH * S * D;
    bf16* vtt  = kp + (size_t)BH * S * D;
    bf16* attn = vtt + (size_t)BH * S * D;
    bf16* wb   = qp;   // qp dead after attn_kernel; reuse for bf16 Wo

    proj_kernel<<<dim3(S / 128, BH, 3), 256, 0, stream>>>(values, keys, query, Wv, Wk, Wq, qp, kp, vtt);
    attn_kernel<<<dim3(S / 256, BH), 256, 0, stream>>>(qp, kp, vtt, attn);
    wo_convert<<<dim3((E * E) / 1024), 256, 0, stream>>>(Wo, wb);
    out_gemm<<<dim3(E / 128, (B * S) / 128), 256, 0, stream>>>(attn, wb, bo, out);
}

// Round 6
// 273.760 us; speedup vs baseline: 1.1462x; 1.1462x over previous
//
#include <hip/hip_runtime.h>

#define B 4
#define S 2048
#define H 16
#define D 64
#define E 1024
#define BH (B*H)

typedef __bf16 bf16;
typedef __bf16 bf16x8 __attribute__((ext_vector_type(8)));
typedef __bf16 bf16x4 __attribute__((ext_vector_type(4)));
typedef float  f32x4  __attribute__((ext_vector_type(4)));

__device__ __forceinline__ f32x4 mfma16(bf16x8 a, bf16x8 b, f32x4 c) {
    return __builtin_amdgcn_mfma_f32_16x16x32_bf16(a, b, c, 0, 0, 0);
}

#define SCALE 0.04508422002778f   // (1/sqrt(1024)) * log2(e), folded into Q

// ---------------------------------------------------------------------------
// Kernel 1: QKV projection (R3 structure) + fused Wo fp32->bf16 (type 3).
// Block = (x-tile, bh, type); 4 waves x 32 rows for types 0-2.
// type 0: query@Wq^T (pre-scaled) -> qp [bh][s][d]   (swapped operands, b64)
// type 1: keys@Wk^T -> kp [bh][s][d]                 (swapped operands, b64)
// type 2: values@Wv^T -> vt [bh][d][s]
// type 3: Wo fp32 -> bf16 (grid x*y = 1024 blocks x 1024 floats = E*E)
// ---------------------------------------------------------------------------
__global__ __launch_bounds__(256) void proj_kernel(
    const float* __restrict__ values, const float* __restrict__ keys,
    const float* __restrict__ query,  const float* __restrict__ Wv,
    const float* __restrict__ Wk,     const float* __restrict__ Wq,
    const float* __restrict__ Wo,
    bf16* __restrict__ qp, bf16* __restrict__ kp, bf16* __restrict__ vt,
    bf16* __restrict__ wb)
{
    const int t    = threadIdx.x;
    const int bh   = blockIdx.y;
    const int type = blockIdx.z;

    if (type == 3) {
        int idx = (bh * 16 + blockIdx.x) * 1024 + t * 4;
        f32x4 v = *(const f32x4*)(Wo + idx);
        *(bf16x4*)(wb + idx) = __builtin_convertvector(v, bf16x4);
        return;
    }

    const int b = bh >> 4, h = bh & 15;
    const int s0 = blockIdx.x * 128;
    const int w = t >> 6, lane = t & 63;
    const int m = lane & 15, g = lane >> 4;
    const int row0 = s0 + w * 32;

    const float* X = (type == 0) ? query : (type == 1) ? keys : values;
    const float* W = (type == 0) ? Wq    : (type == 1) ? Wk   : Wv;

    bf16x8 xa[2][2];
    #pragma unroll
    for (int mt = 0; mt < 2; ++mt)
        #pragma unroll
        for (int kb = 0; kb < 2; ++kb) {
            const float* px = X + (size_t)(b * S + row0 + mt * 16 + m) * E + h * D + kb * 32 + g * 8;
            f32x4 lo = *(const f32x4*)px;
            f32x4 hi = *(const f32x4*)(px + 4);
            if (type == 0) { lo *= SCALE; hi *= SCALE; }
            bf16x8 f;
            #pragma unroll
            for (int i = 0; i < 4; ++i) { f[i] = (bf16)lo[i]; f[4 + i] = (bf16)hi[i]; }
            xa[mt][kb] = f;
        }

    bf16x8 wf[4][2];
    #pragma unroll
    for (int nt = 0; nt < 4; ++nt)
        #pragma unroll
        for (int kb = 0; kb < 2; ++kb) {
            const float* pw = W + (nt * 16 + m) * 64 + kb * 32 + g * 8;
            f32x4 lo = *(const f32x4*)pw;
            f32x4 hi = *(const f32x4*)(pw + 4);
            bf16x8 f;
            #pragma unroll
            for (int i = 0; i < 4; ++i) { f[i] = (bf16)lo[i]; f[4 + i] = (bf16)hi[i]; }
            wf[nt][kb] = f;
        }

    if (type == 2) {
        // D[s][d]: lane col = d = nt*16+m, rows s -> b64 along s into vt[bh][d][s]
        #pragma unroll
        for (int mt = 0; mt < 2; ++mt)
            #pragma unroll
            for (int nt = 0; nt < 4; ++nt) {
                f32x4 acc = (f32x4){0.f, 0.f, 0.f, 0.f};
                acc = mfma16(xa[mt][0], wf[nt][0], acc);
                acc = mfma16(xa[mt][1], wf[nt][1], acc);
                bf16x4 pk = __builtin_convertvector(acc, bf16x4);
                *(bf16x4*)(vt + (size_t)(bh * D + nt * 16 + m) * S + row0 + mt * 16 + g * 4) = pk;
            }
    } else {
        // swapped: D[d][s]: lane col = s, rows d -> b64 stores along d
        bf16* out = (type == 0) ? qp : kp;
        #pragma unroll
        for (int mt = 0; mt < 2; ++mt)
            #pragma unroll
            for (int nt = 0; nt < 4; ++nt) {
                f32x4 acc = (f32x4){0.f, 0.f, 0.f, 0.f};
                acc = mfma16(wf[nt][0], xa[mt][0], acc);
                acc = mfma16(wf[nt][1], xa[mt][1], acc);
                bf16x4 pk = __builtin_convertvector(acc, bf16x4);
                *(bf16x4*)(out + (size_t)(bh * S + row0 + mt * 16 + m) * D + nt * 16 + g * 4) = pk;
            }
    }
}

// ---------------------------------------------------------------------------
// Kernel 2: flash attention — R3 structure (best measured: 96.6 us).
// Static softmax, transposed-QK, 32 q-rows/wave, 128-q blocks, LDS-staged
// K/V tiles of 64, per-wave P round-trip, L via ones-MFMA.
// ---------------------------------------------------------------------------
#define PSTR 72

__global__ __launch_bounds__(256, 4) void attn_kernel(
    const bf16* __restrict__ qp, const bf16* __restrict__ kp,
    const bf16* __restrict__ vt, bf16* __restrict__ attn)
{
    const int t  = threadIdx.x;
    const int bh = blockIdx.y;
    const int b  = bh >> 4, h = bh & 15;
    const int q0 = blockIdx.x * 128;
    const int w  = t >> 6, lane = t & 63;
    const int m  = lane & 15, g = lane >> 4;

    __shared__ bf16 Ks[64 * 72];        // [key][d]
    __shared__ bf16 Vs[64 * 72];        // [d][key]
    __shared__ bf16 Ps[4][32 * PSTR];   // per-wave P [q_local][key_local]

    bf16x8 qa[2][2];
    #pragma unroll
    for (int mt = 0; mt < 2; ++mt)
        #pragma unroll
        for (int kb = 0; kb < 2; ++kb)
            qa[mt][kb] = *(const bf16x8*)(qp + (size_t)(bh * S + q0 + w * 32 + mt * 16 + m) * D + kb * 32 + g * 8);

    bf16x8 ones;
    #pragma unroll
    for (int i = 0; i < 8; ++i) ones[i] = (bf16)1.0f;

    f32x4 O[2][4], L[2];
    #pragma unroll
    for (int mt = 0; mt < 2; ++mt) {
        L[mt] = (f32x4){0.f, 0.f, 0.f, 0.f};
        #pragma unroll
        for (int dt = 0; dt < 4; ++dt) O[mt][dt] = (f32x4){0.f, 0.f, 0.f, 0.f};
    }

    for (int kt = 0; kt < S / 64; ++kt) {
        __syncthreads();
        #pragma unroll
        for (int p = 0; p < 2; ++p) {
            int id = p * 256 + t;
            int row = id >> 3, ch = (id & 7) * 8;
            *(bf16x8*)(Ks + row * 72 + ch) =
                *(const bf16x8*)(kp + (size_t)(bh * S + kt * 64 + row) * D + ch);
            *(bf16x8*)(Vs + row * 72 + ch) =
                *(const bf16x8*)(vt + (size_t)(bh * D + row) * S + kt * 64 + ch);
        }
        __syncthreads();

        // ---- E^T = K Q^T; exp2; b64 P stores (4 consecutive keys/lane) ----
        #pragma unroll
        for (int nt = 0; nt < 4; ++nt) {
            bf16x8 kf0 = *(const bf16x8*)(Ks + (nt * 16 + m) * 72 + g * 8);
            bf16x8 kf1 = *(const bf16x8*)(Ks + (nt * 16 + m) * 72 + 32 + g * 8);
            #pragma unroll
            for (int mt = 0; mt < 2; ++mt) {
                f32x4 et = (f32x4){0.f, 0.f, 0.f, 0.f};
                et = mfma16(kf0, qa[mt][0], et);
                et = mfma16(kf1, qa[mt][1], et);
                bf16x4 pkt;
                #pragma unroll
                for (int i = 0; i < 4; ++i)
                    pkt[i] = (bf16)__builtin_amdgcn_exp2f(et[i]);
                *(bf16x4*)(&Ps[w][(mt * 16 + m) * PSTR + nt * 16 + g * 4]) = pkt;
            }
        }
        // per-wave private LDS region; same-wave ds ordering via lgkmcnt

        bf16x8 pa[2][2];
        #pragma unroll
        for (int mt = 0; mt < 2; ++mt)
            #pragma unroll
            for (int kb = 0; kb < 2; ++kb)
                pa[mt][kb] = *(const bf16x8*)(&Ps[w][(mt * 16 + m) * PSTR + kb * 32 + g * 8]);

        // ---- O += P V ; L += P * ones (MFMA pipe, C-layout aligned) ----
        #pragma unroll
        for (int dt = 0; dt < 4; ++dt) {
            bf16x8 vf0 = *(const bf16x8*)(Vs + (dt * 16 + m) * 72 + g * 8);
            bf16x8 vf1 = *(const bf16x8*)(Vs + (dt * 16 + m) * 72 + 32 + g * 8);
            #pragma unroll
            for (int mt = 0; mt < 2; ++mt) {
                O[mt][dt] = mfma16(pa[mt][0], vf0, O[mt][dt]);
                O[mt][dt] = mfma16(pa[mt][1], vf1, O[mt][dt]);
            }
        }
        #pragma unroll
        for (int mt = 0; mt < 2; ++mt) {
            L[mt] = mfma16(pa[mt][0], ones, L[mt]);
            L[mt] = mfma16(pa[mt][1], ones, L[mt]);
        }
    }

    #pragma unroll
    for (int mt = 0; mt < 2; ++mt) {
        f32x4 linv;
        #pragma unroll
        for (int i = 0; i < 4; ++i) linv[i] = 1.f / L[mt][i];
        #pragma unroll
        for (int dt = 0; dt < 4; ++dt)
            #pragma unroll
            for (int i = 0; i < 4; ++i)
                attn[(size_t)(b * S + q0 + w * 32 + mt * 16 + g * 4 + i) * E + h * D + dt * 16 + m] =
                    (bf16)(O[mt][dt][i] * linv[i]);
    }
}

// ---------------------------------------------------------------------------
// Kernel 3: out = attn @ Wo^T + bo. 128m x 64n tiles, BK=64 -> 1024 blocks
// (4 blocks/CU vs previous 2). Swapped operands (Wo as A) for f32x4 stores;
// register prefetch of next K-slab.
// ---------------------------------------------------------------------------
__global__ __launch_bounds__(256, 4) void out_gemm(
    const bf16* __restrict__ A, const bf16* __restrict__ wo,
    const float* __restrict__ bo, float* __restrict__ out)
{
    const int t  = threadIdx.x;
    const int n0 = blockIdx.x * 64;
    const int m0 = blockIdx.y * 128;
    const int w  = t >> 6, lane = t & 63;
    const int m  = lane & 15, g = lane >> 4;
    const int wm = w >> 1, wn = w & 1;   // 2x2 waves over 64m x 32n

    __shared__ bf16 As[128 * 72];
    __shared__ bf16 Bs[64 * 72];

    f32x4 acc[4][2];
    #pragma unroll
    for (int mt = 0; mt < 4; ++mt)
        #pragma unroll
        for (int nt = 0; nt < 2; ++nt) acc[mt][nt] = (f32x4){0.f, 0.f, 0.f, 0.f};

    bf16x8 pA[4], pB[2];
    #pragma unroll
    for (int p = 0; p < 4; ++p) {
        int id = p * 256 + t;
        pA[p] = *(const bf16x8*)(A + (size_t)(m0 + (id >> 3)) * E + (id & 7) * 8);
    }
    #pragma unroll
    for (int p = 0; p < 2; ++p) {
        int id = p * 256 + t;
        pB[p] = *(const bf16x8*)(wo + (size_t)(n0 + (id >> 3)) * E + (id & 7) * 8);
    }

    for (int kt = 0; kt < E / 64; ++kt) {
        __syncthreads();
        #pragma unroll
        for (int p = 0; p < 4; ++p) {
            int id = p * 256 + t;
            *(bf16x8*)(As + (id >> 3) * 72 + (id & 7) * 8) = pA[p];
        }
        #pragma unroll
        for (int p = 0; p < 2; ++p) {
            int id = p * 256 + t;
            *(bf16x8*)(Bs + (id >> 3) * 72 + (id & 7) * 8) = pB[p];
        }
        __syncthreads();
        if (kt + 1 < E / 64) {
            #pragma unroll
            for (int p = 0; p < 4; ++p) {
                int id = p * 256 + t;
                pA[p] = *(const bf16x8*)(A + (size_t)(m0 + (id >> 3)) * E + (kt + 1) * 64 + (id & 7) * 8);
            }
            #pragma unroll
            for (int p = 0; p < 2; ++p) {
                int id = p * 256 + t;
                pB[p] = *(const bf16x8*)(wo + (size_t)(n0 + (id >> 3)) * E + (kt + 1) * 64 + (id & 7) * 8);
            }
        }

        #pragma unroll
        for (int kb = 0; kb < 2; ++kb) {
            bf16x8 af[4], bfr[2];
            #pragma unroll
            for (int mt = 0; mt < 4; ++mt)
                af[mt] = *(const bf16x8*)(As + (wm * 64 + mt * 16 + m) * 72 + kb * 32 + g * 8);
            #pragma unroll
            for (int nt = 0; nt < 2; ++nt)
                bfr[nt] = *(const bf16x8*)(Bs + (wn * 32 + nt * 16 + m) * 72 + kb * 32 + g * 8);
            #pragma unroll
            for (int mt = 0; mt < 4; ++mt)
                #pragma unroll
                for (int nt = 0; nt < 2; ++nt)
                    acc[mt][nt] = mfma16(bfr[nt], af[mt], acc[mt][nt]);
        }
    }

    #pragma unroll
    for (int mt = 0; mt < 4; ++mt)
        #pragma unroll
        for (int nt = 0; nt < 2; ++nt) {
            f32x4 bias = *(const f32x4*)(bo + n0 + wn * 32 + nt * 16 + g * 4);
            f32x4 res = acc[mt][nt] + bias;
            *(f32x4*)(out + (size_t)(m0 + wm * 64 + mt * 16 + m) * E + n0 + wn * 32 + nt * 16 + g * 4) = res;
        }
}

// ---------------------------------------------------------------------------
extern "C" void kernel_launch(void* const* d_in, const int* in_sizes, int n_in,
                              void* d_out, int out_size, void* d_ws, size_t ws_size,
                              hipStream_t stream) {
    const float* values = (const float*)d_in[0];
    const float* keys   = (const float*)d_in[1];
    const float* query  = (const float*)d_in[2];
    const float* Wv     = (const float*)d_in[3];
    const float* Wk     = (const float*)d_in[4];
    const float* Wq     = (const float*)d_in[5];
    const float* Wo     = (const float*)d_in[6];
    const float* bo     = (const float*)d_in[7];
    float* out = (float*)d_out;

    bf16* qp   = (bf16*)d_ws;
    bf16* kp   = qp  + (size_t)BH * S * D;
    bf16* vt   = kp  + (size_t)BH * S * D;
    bf16* attn = vt  + (size_t)BH * S * D;
    bf16* wb   = attn + (size_t)BH * S * D;   // 2 MB for bf16 Wo

    proj_kernel<<<dim3(S / 128, BH, 4), 256, 0, stream>>>(
        values, keys, query, Wv, Wk, Wq, Wo, qp, kp, vt, wb);
    attn_kernel<<<dim3(S / 128, BH), 256, 0, stream>>>(qp, kp, vt, attn);
    out_gemm<<<dim3(E / 64, (B * S) / 128), 256, 0, stream>>>(attn, wb, bo, out);
}